// Round 3
// 483.213 us; speedup vs baseline: 1.2106x; 1.2106x over previous
//
#include <hip/hip_runtime.h>

// GRU: B=4096, T=512, I=32, H=64. One WG per 16-batch tile, 4 waves.
// Wave w owns hidden slice [w*16, w*16+16) for all 3 gates.
// hp^T = W_hh * h^T: A = weight rows in registers, B = h^T from LDS.
//
// R5b: compiler-proof burst loads (R5 resubmit with robustness fixes;
// this round: verbatim resubmit — R2 failure was GPU acquisition
// timeout, kernel never ran).
// R4's register queue was defeated: the compiler sank the float4 burst
// loads to their per-step use points (VGPR_Count=124 vs ~220 expected),
// so every step had an outstanding global load drained by the
// s_waitcnt vmcnt(0) that __syncthreads() emits -> ~1000 cyc/step stall
// (measured 1580 cyc/step vs ~450 chain). Fix:
//  - seq loads issued via inline-asm global_load_dwordx4 (invisible to
//    the compiler's waitcnt scoreboard), 16 loads per 8-step chunk,
//    8 steps of prefetch distance (~2500+ cyc cover >> ~900 cyc HBM).
//    Issued as 8 two-load asm blocks (2 outputs + 1 addr each)
//    instead of one 16-output/64-VGPR asm statement, to keep register
//    allocation trivial at ~230-VGPR pressure.
//  - drained by a manual "s_waitcnt vmcnt(0)" asm that ties all 16
//    destination vectors as "+v" operands (data-dep: uses can't hoist).
//  - __syncthreads() replaced by s_waitcnt lgkmcnt(0) + raw s_barrier
//    (m201/T4 pattern): no compiler vmcnt(0) at barriers, so the asm
//    loads stay in flight across them. Zero tracked vmem in the loop.
//    The lgkmcnt asm carries a "memory" clobber so the hOut ds_write
//    can't be sunk past the barrier (cross-wave race).
// __launch_bounds__(256,1): occupancy is structurally 1 wave/SIMD
// (256 batch-tiles x 4 waves = 1024 waves = exactly fills 256 CUs),
// so the ~230-VGPR register queue costs nothing.

#define TSTEPS 512
#define IDIM 32
#define HDIM 64

typedef __bf16 bf16x8 __attribute__((ext_vector_type(8)));
typedef __bf16 bf16x4 __attribute__((ext_vector_type(4)));
typedef float f32x4 __attribute__((ext_vector_type(4)));

#define NLOG2E -1.4426950408889634f
#define TWOLOG2E 2.8853900817779268f

// Two untracked 16B loads (one timestep slice per lane = 8 floats =
// 2x float4) from base+literal offsets.
#define LOADPAIR(dst0, dst1, ptr, off)                                     \
    asm volatile("global_load_dwordx4 %0, %2, off offset:%c3\n\t"          \
                 "global_load_dwordx4 %1, %2, off offset:%c4"              \
        : "=&v"(dst0), "=&v"(dst1)                                         \
        : "v"(ptr), "i"(off), "i"((off) + 16));

// Issue one 8-timestep chunk (1 KiB contiguous per lane) as 16 untracked
// global_load_dwordx4. Stride between timesteps = IDIM*4 = 128 B.
#define ISSUE_CHUNK(qq, baseT) do {                                        \
    const float* _p = seqRow + (size_t)(baseT) * IDIM;                     \
    LOADPAIR(qq[0][0], qq[0][1], _p, 0)                                    \
    LOADPAIR(qq[1][0], qq[1][1], _p, 128)                                  \
    LOADPAIR(qq[2][0], qq[2][1], _p, 256)                                  \
    LOADPAIR(qq[3][0], qq[3][1], _p, 384)                                  \
    LOADPAIR(qq[4][0], qq[4][1], _p, 512)                                  \
    LOADPAIR(qq[5][0], qq[5][1], _p, 640)                                  \
    LOADPAIR(qq[6][0], qq[6][1], _p, 768)                                  \
    LOADPAIR(qq[7][0], qq[7][1], _p, 896)                                  \
} while (0)

// Drain the untracked loads; tie all destinations so no consumer can be
// scheduled above the wait (true data dependence, not a "memory" clobber).
#define WAITDEP(qq)                                                        \
    asm volatile("s_waitcnt vmcnt(0)"                                      \
        : "+v"(qq[0][0]), "+v"(qq[0][1]), "+v"(qq[1][0]), "+v"(qq[1][1]), \
          "+v"(qq[2][0]), "+v"(qq[2][1]), "+v"(qq[3][0]), "+v"(qq[3][1]), \
          "+v"(qq[4][0]), "+v"(qq[4][1]), "+v"(qq[5][0]), "+v"(qq[5][1]), \
          "+v"(qq[6][0]), "+v"(qq[6][1]), "+v"(qq[7][0]), "+v"(qq[7][1]))

// Raw barrier: LDS drained manually; NO vmcnt drain (the whole point).
// "memory" clobber pins DS ops (esp. the hOut ds_write) on the correct
// side of the barrier; it does NOT make the compiler emit vmcnt waits
// (it tracks zero vmem ops in the loop - all are inside asm).
#define WG_BARRIER() do {                                                  \
    asm volatile("s_waitcnt lgkmcnt(0)" ::: "memory");                     \
    __builtin_amdgcn_s_barrier();                                          \
} while (0)

__global__ __launch_bounds__(256, 1) void gru_fused_kernel(
    const float* __restrict__ seq, const float* __restrict__ W_ih,
    const float* __restrict__ W_hh, const float* __restrict__ b_ih,
    const float* __restrict__ b_hh, float* __restrict__ out)
{
    __shared__ __bf16 hB[2][16][72];  // h^T double-buffered; 144 B row stride

    const int tid  = threadIdx.x;
    const int w    = tid >> 6;
    const int lane = tid & 63;
    const int l    = lane & 15;       // batch col
    const int q    = lane >> 4;       // quad
    const int b0   = blockIdx.x * 16;

    for (int i = tid; i < 2 * 16 * 72; i += 256)
        (&hB[0][0][0])[i] = (__bf16)0.0f;

    // ---- A-fragments; r,z gates pre-scaled by -log2e ----
    bf16x8 aH[3][2], aI[3];
    #pragma unroll
    for (int g = 0; g < 3; ++g) {
        const float scl = (g < 2) ? NLOG2E : 1.0f;
        const int row = g * 64 + w * 16 + l;
        #pragma unroll
        for (int kc = 0; kc < 2; ++kc) {
            const float* p = W_hh + row * HDIM + kc * 32 + q * 8;
            #pragma unroll
            for (int j = 0; j < 8; ++j) aH[g][kc][j] = (__bf16)(scl * p[j]);
        }
        const float* pi = W_ih + row * IDIM + q * 8;
        #pragma unroll
        for (int j = 0; j < 8; ++j) aI[g][j] = (__bf16)(scl * pi[j]);
    }

    // ---- bias C-init vectors at this lane's C/D rows (hidden = w*16+4q+r) ----
    f32x4 biasR4, biasZ4, biasXN4, biasHN4;
    #pragma unroll
    for (int r = 0; r < 4; ++r) {
        const int g = w * 16 + 4 * q + r;
        biasR4[r]  = NLOG2E * (b_ih[g]      + b_hh[g]);
        biasZ4[r]  = NLOG2E * (b_ih[64 + g] + b_hh[64 + g]);
        biasXN4[r] = b_ih[128 + g];
        biasHN4[r] = b_hh[128 + g];
    }

    float h[4] = {0.f, 0.f, 0.f, 0.f};

    const float* seqRow = seq + ((size_t)(b0 + l) * TSTEPS) * IDIM + q * 8;

    // ---- 8-step register queues, loaded ONLY via untracked asm loads.
    // qA holds the even chunk (steps tc..tc+7), qB the odd (tc+8..tc+15).
    f32x4 qA[8][2], qB[8][2];
    ISSUE_CHUNK(qA, 0);
    ISSUE_CHUNK(qB, 8);
    WAITDEP(qA);            // vmcnt(0): one-time drain of both chunks
    WAITDEP(qB);            // free (already 0); establishes qB data-dep

    WG_BARRIER();           // hB zero-init visible

    // ---- t=0 x-part (bias-init C) ----
    bf16x8 xb;
    #pragma unroll
    for (int j = 0; j < 4; ++j) {
        xb[j]     = (__bf16)qA[0][0][j];
        xb[4 + j] = (__bf16)qA[0][1][j];
    }
    f32x4 accR  = __builtin_amdgcn_mfma_f32_16x16x32_bf16(aI[0], xb, biasR4, 0, 0, 0);
    f32x4 accZ  = __builtin_amdgcn_mfma_f32_16x16x32_bf16(aI[1], xb, biasZ4, 0, 0, 0);
    f32x4 accXN = __builtin_amdgcn_mfma_f32_16x16x32_bf16(aI[2], xb, biasXN4, 0, 0, 0);

    for (int tc = 0; tc < TSTEPS; tc += 16) {
        #pragma unroll
        for (int s = 0; s < 16; ++s) {
            const int buf = s & 1;  // tc is a multiple of 16

            // post-barrier critical path: h^T fragments
            bf16x8 hb0 = *(const bf16x8*)&hB[buf][l][q * 8];
            bf16x8 hb1 = *(const bf16x8*)&hB[buf][l][32 + q * 8];

            accR = __builtin_amdgcn_mfma_f32_16x16x32_bf16(aH[0][0], hb0, accR, 0, 0, 0);
            accR = __builtin_amdgcn_mfma_f32_16x16x32_bf16(aH[0][1], hb1, accR, 0, 0, 0);
            accZ = __builtin_amdgcn_mfma_f32_16x16x32_bf16(aH[1][0], hb0, accZ, 0, 0, 0);
            accZ = __builtin_amdgcn_mfma_f32_16x16x32_bf16(aH[1][1], hb1, accZ, 0, 0, 0);
            f32x4 accHN = __builtin_amdgcn_mfma_f32_16x16x32_bf16(aH[2][0], hb0, biasHN4, 0, 0, 0);
            accHN = __builtin_amdgcn_mfma_f32_16x16x32_bf16(aH[2][1], hb1, accHN, 0, 0, 0);

            bf16x4 hOut;
            #pragma unroll
            for (int r = 0; r < 4; ++r) {
                // accR/accZ already = -log2e * (pre-activation incl. bias)
                const float rg = __builtin_amdgcn_rcpf(1.0f + __builtin_amdgcn_exp2f(accR[r]));
                const float zg = __builtin_amdgcn_rcpf(1.0f + __builtin_amdgcn_exp2f(accZ[r]));
                const float v  = accXN[r] + rg * accHN[r];
                const float u  = __builtin_amdgcn_exp2f(TWOLOG2E * v);
                const float ng = 1.0f - 2.0f * __builtin_amdgcn_rcpf(1.0f + u);
                h[r] = ng + zg * (h[r] - ng);
                hOut[r] = (__bf16)h[r];
            }
            *(bf16x4*)&hB[buf ^ 1][l][w * 16 + 4 * q] = hOut;

            // burst pipeline: drain the chunk first needed THIS step (issued
            // 8 steps ago, ~2500+ cyc of cover), then issue the next chunk.
            // All other barriers see zero outstanding vmem.
            if (s == 7) {
                WAITDEP(qB);                              // chunk tc+8 ready
                if (tc + 16 < TSTEPS) ISSUE_CHUNK(qA, tc + 16);
            }
            if (s == 15) {
                WAITDEP(qA);                              // chunk tc+16 ready
                if (tc + 24 < TSTEPS) ISSUE_CHUNK(qB, tc + 24);
            }

            // ---- pre-barrier work for t+1 (h-independent): cvt + x-proj MFMAs ----
            // s+1: slot (s+1)&7 of qA if (s+1)<8 else qB; at s==15 uses qA[0]
            // (refilled with chunk tc+16 at s==7, drained just above). Final
            // step computes a dead x-proj for t=512 from stale regs — harmless.
            {
                const int s1 = s + 1;
                const f32x4* x0 = (s1 < 8) ? &qA[s1 & 7][0]
                                           : (s1 < 16) ? &qB[s1 & 7][0]
                                                       : &qA[0][0];
                bf16x8 xb1;
                #pragma unroll
                for (int j = 0; j < 4; ++j) {
                    xb1[j]     = (__bf16)x0[0][j];
                    xb1[4 + j] = (__bf16)x0[1][j];
                }
                accR  = __builtin_amdgcn_mfma_f32_16x16x32_bf16(aI[0], xb1, biasR4, 0, 0, 0);
                accZ  = __builtin_amdgcn_mfma_f32_16x16x32_bf16(aI[1], xb1, biasZ4, 0, 0, 0);
                accXN = __builtin_amdgcn_mfma_f32_16x16x32_bf16(aI[2], xb1, biasXN4, 0, 0, 0);
            }

            WG_BARRIER();
        }
    }

    float4 o = {h[0], h[1], h[2], h[3]};
    *(float4*)&out[(size_t)(b0 + l) * HDIM + w * 16 + 4 * q] = o;
}

extern "C" void kernel_launch(void* const* d_in, const int* in_sizes, int n_in,
                              void* d_out, int out_size, void* d_ws, size_t ws_size,
                              hipStream_t stream) {
    const float* seq  = (const float*)d_in[0];
    const float* W_ih = (const float*)d_in[1];
    const float* W_hh = (const float*)d_in[2];
    const float* b_ih = (const float*)d_in[3];
    const float* b_hh = (const float*)d_in[4];
    float* out = (float*)d_out;
    gru_fused_kernel<<<256, 256, 0, stream>>>(seq, W_ih, W_hh, b_ih, b_hh, out);
}